// Round 6
// baseline (392.565 us; speedup 1.0000x reference)
//
#include <hip/hip_runtime.h>

#define HEADS 16
#define DHEAD 64
#define BATCH 2
#define SEQ   2048
#define DIM   1024
#define ROWS  (BATCH*SEQ)      // 4096
#define SCALE_LOG2E 0.180336880f   // 0.125 * log2(e)

typedef short v8s __attribute__((ext_vector_type(8)));
typedef float v4f __attribute__((ext_vector_type(4)));

__device__ __forceinline__ float fast_exp2(float x) {
    return __builtin_amdgcn_exp2f(x);   // v_exp_f32: D = 2^S0
}

__device__ __forceinline__ unsigned short f2bf(float f) {
    unsigned u = __float_as_uint(f);
    u += 0x7FFFu + ((u >> 16) & 1u);   // RNE
    return (unsigned short)(u >> 16);
}

// ---------------- LayerNorm: one block per row, bf16 out ----------------
__global__ __launch_bounds__(256) void ln_kernel(const float* __restrict__ x,
                                                 const float* __restrict__ gamma,
                                                 const float* __restrict__ beta,
                                                 unsigned short* __restrict__ xn) {
    int row = blockIdx.x;
    const float* xr = x + (size_t)row * DIM;
    int t = threadIdx.x;
    float4 v = *(const float4*)(xr + t * 4);
    float s  = v.x + v.y + v.z + v.w;
    float sq = v.x * v.x + v.y * v.y + v.z * v.z + v.w * v.w;
#pragma unroll
    for (int off = 32; off > 0; off >>= 1) {
        s  += __shfl_down(s,  off, 64);
        sq += __shfl_down(sq, off, 64);
    }
    __shared__ float ss[4], ssq[4];
    int wave = t >> 6, lane = t & 63;
    if (lane == 0) { ss[wave] = s; ssq[wave] = sq; }
    __syncthreads();
    float tot  = ss[0] + ss[1] + ss[2] + ss[3];
    float totq = ssq[0] + ssq[1] + ssq[2] + ssq[3];
    float mean = tot * (1.f / DIM);
    float var  = totq * (1.f / DIM) - mean * mean;
    float rstd = rsqrtf(var + 1e-5f);
    float4 g = *(const float4*)(gamma + t * 4);
    float4 bb = *(const float4*)(beta + t * 4);
    ushort4 o;
    o.x = f2bf((v.x - mean) * rstd * g.x + bb.x);
    o.y = f2bf((v.y - mean) * rstd * g.y + bb.y);
    o.z = f2bf((v.z - mean) * rstd * g.z + bb.z);
    o.w = f2bf((v.w - mean) * rstd * g.w + bb.w);
    *(ushort4*)(xn + (size_t)row * DIM + t * 4) = o;
}

// ---------------- Transpose + f32->bf16: Wt[n][k] = W[k][n] ----------------
__global__ __launch_bounds__(256) void tr_kernel(const float* __restrict__ W,
                                                 unsigned short* __restrict__ Wt,
                                                 int Kw, int Nw) {
    __shared__ float tile[64][65];
    int n0 = blockIdx.x * 64, k0 = blockIdx.y * 64;
    int tid = threadIdx.x;
#pragma unroll
    for (int l = 0; l < 4; ++l) {
        int kk = (tid >> 4) + l * 16;
        int nn = (tid & 15) * 4;
        float4 v = *(const float4*)(W + (size_t)(k0 + kk) * Nw + n0 + nn);
        tile[kk][nn + 0] = v.x; tile[kk][nn + 1] = v.y;
        tile[kk][nn + 2] = v.z; tile[kk][nn + 3] = v.w;
    }
    __syncthreads();
#pragma unroll
    for (int l = 0; l < 4; ++l) {
        int cid = tid + l * 256;
        int nn = cid >> 4, kc = (cid & 15) * 4;
        ushort4 o;
        o.x = f2bf(tile[kc + 0][nn]);
        o.y = f2bf(tile[kc + 1][nn]);
        o.z = f2bf(tile[kc + 2][nn]);
        o.w = f2bf(tile[kc + 3][nn]);
        *(ushort4*)(Wt + (size_t)(n0 + nn) * Kw + k0 + kc) = o;
    }
}

// ---------------- LDS-staged MFMA GEMM core ----------------
// BM=128, BK=32. BN=128: wave=64x64 (MI=4, bOff by wave); BN=64: wave=32x64 (MI=2).
// LDS tiles padded to stride 40 shorts (80 B): read/write bank aliasing is uniform 2-way (free).
template<int BN>
__device__ __forceinline__ void mm_core2(const unsigned short* __restrict__ A,
                                         const unsigned short* __restrict__ Bt,
                                         int K, int aTile, int bTile,
                                         unsigned short (*As)[40],
                                         unsigned short (*Bs)[40],
                                         v4f (*acc)[4]) {
    constexpr int MI = (BN == 128) ? 4 : 2;
    int t = threadIdx.x;
    int w = t >> 6, L = t & 63, l15 = L & 15, quad = L >> 4;
    int aOff = (BN == 128) ? (w >> 1) * 64 : w * 32;
    int bOff = (BN == 128) ? (w & 1) * 64 : 0;
    for (int k0 = 0; k0 < K; k0 += 32) {
        __syncthreads();    // previous tile fully consumed
        // stage A: 128 rows x 4 chunks(16B) = 512 chunks, 2 per thread
#pragma unroll
        for (int j = 0; j < 2; ++j) {
            int cid = t + j * 256;
            int row = cid >> 2, c = cid & 3;
            *(v8s*)&As[row][c * 8] =
                *(const v8s*)(A + (size_t)(aTile + row) * K + k0 + c * 8);
        }
        // stage B: BN rows x 4 chunks
#pragma unroll
        for (int j = 0; j < BN / 64; ++j) {
            int cid = t + j * 256;
            int row = cid >> 2, c = cid & 3;
            *(v8s*)&Bs[row][c * 8] =
                *(const v8s*)(Bt + (size_t)(bTile + row) * K + k0 + c * 8);
        }
        __syncthreads();    // tile visible
        v8s a[MI], b[4];
#pragma unroll
        for (int i = 0; i < MI; ++i) a[i] = *(const v8s*)&As[aOff + i * 16 + l15][quad * 8];
#pragma unroll
        for (int j = 0; j < 4; ++j) b[j] = *(const v8s*)&Bs[bOff + j * 16 + l15][quad * 8];
#pragma unroll
        for (int i = 0; i < MI; ++i)
#pragma unroll
            for (int j = 0; j < 4; ++j)
                acc[i][j] = __builtin_amdgcn_mfma_f32_16x16x32_bf16(a[i], b[j], acc[i][j], 0, 0, 0);
    }
}

// ---------------- GEMM -> q_h/k_h [b][h][seq][64] bf16 (BN=128) ----------------
__global__ __launch_bounds__(256) void gemm_qk_kernel(const unsigned short* __restrict__ A,
                                                      const unsigned short* __restrict__ Bt,
                                                      unsigned short* __restrict__ q_h,
                                                      unsigned short* __restrict__ k_h) {
    __shared__ __align__(16) unsigned short As[128][40];
    __shared__ __align__(16) unsigned short Bs[128][40];
    int t = threadIdx.x, w = t >> 6, L = t & 63, l15 = L & 15, quad = L >> 4;
    int aTile = blockIdx.y * 128, bTile = blockIdx.x * 128;
    int aOff = (w >> 1) * 64, bOff = (w & 1) * 64;
    v4f acc[4][4] = {};
    mm_core2<128>(A, Bt, DIM, aTile, bTile, As, Bs, acc);
#pragma unroll
    for (int j = 0; j < 4; ++j) {
        int col = bTile + bOff + j * 16 + l15;
        unsigned short* dst = (col < 1024) ? q_h : k_h;
        int c = col & 1023;
        int h = c >> 6, d = c & 63;
#pragma unroll
        for (int i = 0; i < 4; ++i) {
#pragma unroll
            for (int r = 0; r < 4; ++r) {
                int m = aTile + aOff + i * 16 + quad * 4 + r;
                int b = m >> 11, seq = m & 2047;
                dst[(((size_t)(b * 16 + h)) * SEQ + seq) * 64 + d] = f2bf(acc[i][j][r]);
            }
        }
    }
}

// ---------------- GEMM -> v_t [b][h][64][seq] bf16 transposed (BN=64) ----------------
__global__ __launch_bounds__(256) void gemm_v_kernel(const unsigned short* __restrict__ A,
                                                     const unsigned short* __restrict__ Bt,
                                                     unsigned short* __restrict__ v_t) {
    __shared__ __align__(16) unsigned short As[128][40];
    __shared__ __align__(16) unsigned short Bs[64][40];
    int t = threadIdx.x, w = t >> 6, L = t & 63, l15 = L & 15, quad = L >> 4;
    int aTile = blockIdx.y * 128, bTile = blockIdx.x * 64;
    v4f acc[2][4] = {};
    mm_core2<64>(A, Bt, DIM, aTile, bTile, As, Bs, acc);
#pragma unroll
    for (int j = 0; j < 4; ++j) {
        int c = bTile + j * 16 + l15;
        int h = c >> 6, d = c & 63;
#pragma unroll
        for (int i = 0; i < 2; ++i) {
            int m0 = aTile + w * 32 + i * 16 + quad * 4;
            int b = m0 >> 11, seq0 = m0 & 2047;
            ushort4 o;
            o.x = f2bf(acc[i][j][0]); o.y = f2bf(acc[i][j][1]);
            o.z = f2bf(acc[i][j][2]); o.w = f2bf(acc[i][j][3]);
            *(ushort4*)(v_t + (((size_t)(b * 16 + h)) * 64 + d) * SEQ + seq0) = o;
        }
    }
}

// ---------------- Final GEMM + bias, f32 out (BN=64) ----------------
__global__ __launch_bounds__(256) void gemm_out_kernel(const unsigned short* __restrict__ A,
                                                       const unsigned short* __restrict__ Bt,
                                                       const float* __restrict__ bias,
                                                       float* __restrict__ C) {
    __shared__ __align__(16) unsigned short As[128][40];
    __shared__ __align__(16) unsigned short Bs[64][40];
    int t = threadIdx.x, w = t >> 6, L = t & 63, l15 = L & 15, quad = L >> 4;
    int aTile = blockIdx.y * 128, bTile = blockIdx.x * 64;
    v4f acc[2][4] = {};
    mm_core2<64>(A, Bt, DIM, aTile, bTile, As, Bs, acc);
#pragma unroll
    for (int j = 0; j < 4; ++j) {
        int col = bTile + j * 16 + l15;
        float bv = bias[col];
#pragma unroll
        for (int i = 0; i < 2; ++i)
#pragma unroll
            for (int r = 0; r < 4; ++r) {
                int m = aTile + w * 32 + i * 16 + quad * 4 + r;
                C[(size_t)m * DIM + col] = acc[i][j][r] + bv;
            }
    }
}

// ---------------- MFMA flash attention, no online-softmax ----------------
// block = 64 Q rows (grid 1024 -> 4 blocks/CU); wave = 16 Q rows; 64 keys / iter.
// exp without max subtraction: |s| <= |q||k|/8 ~ 8, no overflow possible in f32.
__global__ __launch_bounds__(256) void attn_kernel(const unsigned short* __restrict__ q_h,
                                                   const unsigned short* __restrict__ k_h,
                                                   const unsigned short* __restrict__ v_t,
                                                   unsigned short* __restrict__ ao) {
    __shared__ __align__(16) unsigned short Pld[4][16 * 72];   // stride 72: 2-way aliasing only
    int qt = blockIdx.x, h = blockIdx.y, b = blockIdx.z;
    int bh = b * HEADS + h;
    int w = threadIdx.x >> 6;
    int L = threadIdx.x & 63, l15 = L & 15, quad = L >> 4;
    int qrow0 = qt * 64 + w * 16;

    const unsigned short* qp = q_h + ((size_t)bh * SEQ + qrow0 + l15) * 64 + quad * 8;
    v8s qf0 = *(const v8s*)(qp);
    v8s qf1 = *(const v8s*)(qp + 32);

    const unsigned short* kp = k_h + ((size_t)bh * SEQ + l15) * 64 + quad * 8;
    const unsigned short* vp = v_t + ((size_t)bh * 64 + l15) * SEQ + quad * 8;

    v4f o[4] = {};
    float lsum[4] = {};

    for (int j0 = 0; j0 < SEQ; j0 += 64) {
        // ---- K fragments for 4 key-tiles ----
        v8s kf[4][2];
#pragma unroll
        for (int jt = 0; jt < 4; ++jt) {
            kf[jt][0] = *(const v8s*)(kp + (size_t)(j0 + jt * 16) * 64);
            kf[jt][1] = *(const v8s*)(kp + (size_t)(j0 + jt * 16) * 64 + 32);
        }
        // ---- S = Q K^T ----
        v4f s[4] = {};
#pragma unroll
        for (int jt = 0; jt < 4; ++jt) {
            s[jt] = __builtin_amdgcn_mfma_f32_16x16x32_bf16(qf0, kf[jt][0], s[jt], 0, 0, 0);
            s[jt] = __builtin_amdgcn_mfma_f32_16x16x32_bf16(qf1, kf[jt][1], s[jt], 0, 0, 0);
        }
        // ---- P = exp(S), per-lane l accumulation, C-layout -> LDS ----
#pragma unroll
        for (int r = 0; r < 4; ++r) {
            float p0 = fast_exp2(s[0][r] * SCALE_LOG2E);
            float p1 = fast_exp2(s[1][r] * SCALE_LOG2E);
            float p2 = fast_exp2(s[2][r] * SCALE_LOG2E);
            float p3 = fast_exp2(s[3][r] * SCALE_LOG2E);
            lsum[r] += (p0 + p1) + (p2 + p3);
            int rb = (quad * 4 + r) * 72 + l15;
            Pld[w][rb]      = f2bf(p0);
            Pld[w][rb + 16] = f2bf(p1);
            Pld[w][rb + 32] = f2bf(p2);
            Pld[w][rb + 48] = f2bf(p3);
        }
        // ---- P back as A-fragments (wave-private LDS, no barrier) ----
        v8s pa0 = *(const v8s*)(&Pld[w][l15 * 72 + quad * 8]);
        v8s pa1 = *(const v8s*)(&Pld[w][l15 * 72 + 32 + quad * 8]);
        // ---- V fragments ----
        v8s vf[4][2];
#pragma unroll
        for (int dt = 0; dt < 4; ++dt) {
            vf[dt][0] = *(const v8s*)(vp + (size_t)dt * 16 * SEQ + j0);
            vf[dt][1] = *(const v8s*)(vp + (size_t)dt * 16 * SEQ + j0 + 32);
        }
        // ---- O += P V ----
#pragma unroll
        for (int dt = 0; dt < 4; ++dt) {
            o[dt] = __builtin_amdgcn_mfma_f32_16x16x32_bf16(pa0, vf[dt][0], o[dt], 0, 0, 0);
            o[dt] = __builtin_amdgcn_mfma_f32_16x16x32_bf16(pa1, vf[dt][1], o[dt], 0, 0, 0);
        }
    }
    // ---- final row-sum reduction (within 16-lane group) + store ----
#pragma unroll
    for (int r = 0; r < 4; ++r) {
        float sm = lsum[r];
        sm += __shfl_xor(sm, 1, 64);
        sm += __shfl_xor(sm, 2, 64);
        sm += __shfl_xor(sm, 4, 64);
        sm += __shfl_xor(sm, 8, 64);
        lsum[r] = 1.f / sm;
    }
#pragma unroll
    for (int r = 0; r < 4; ++r) {
        int rowg = b * SEQ + qt * 64 + w * 16 + quad * 4 + r;
        size_t base = (size_t)rowg * DIM + h * 64 + l15;
        float inv = lsum[r];
        ao[base]      = f2bf(o[0][r] * inv);
        ao[base + 16] = f2bf(o[1][r] * inv);
        ao[base + 32] = f2bf(o[2][r] * inv);
        ao[base + 48] = f2bf(o[3][r] * inv);
    }
}

extern "C" void kernel_launch(void* const* d_in, const int* in_sizes, int n_in,
                              void* d_out, int out_size, void* d_ws, size_t ws_size,
                              hipStream_t stream) {
    const float* x     = (const float*)d_in[0];
    const float* gamma = (const float*)d_in[1];
    const float* beta  = (const float*)d_in[2];
    const float* Wqk   = (const float*)d_in[3];
    const float* Wv    = (const float*)d_in[4];
    const float* Wout  = (const float*)d_in[5];
    const float* bout  = (const float*)d_in[6];
    float* out = (float*)d_out;

    unsigned short* ws = (unsigned short*)d_ws;
    unsigned short* xn    = ws;                            // 4096*1024
    unsigned short* Wt_qk = xn + (size_t)ROWS * DIM;       // 2048*1024
    unsigned short* Wt_v  = Wt_qk + (size_t)2048 * DIM;    // 1024*1024
    unsigned short* Wt_o  = Wt_v + (size_t)DIM * DIM;      // 1024*1024
    unsigned short* q_h   = Wt_o + (size_t)DIM * DIM;      // 4096*1024
    unsigned short* k_h   = q_h + (size_t)ROWS * DIM;      // 4096*1024
    unsigned short* v_t   = k_h + (size_t)ROWS * DIM;      // 4096*1024
    unsigned short* ao    = v_t + (size_t)ROWS * DIM;      // 4096*1024

    ln_kernel<<<ROWS, 256, 0, stream>>>(x, gamma, beta, xn);
    tr_kernel<<<dim3(2048 / 64, DIM / 64), 256, 0, stream>>>(Wqk, Wt_qk, DIM, 2048);
    tr_kernel<<<dim3(DIM / 64, DIM / 64), 256, 0, stream>>>(Wv, Wt_v, DIM, DIM);
    tr_kernel<<<dim3(DIM / 64, DIM / 64), 256, 0, stream>>>(Wout, Wt_o, DIM, DIM);
    gemm_qk_kernel<<<dim3(2048 / 128, ROWS / 128), 256, 0, stream>>>(xn, Wt_qk, q_h, k_h);
    gemm_v_kernel<<<dim3(DIM / 64, ROWS / 128), 256, 0, stream>>>(xn, Wt_v, v_t);
    attn_kernel<<<dim3(SEQ / 64, HEADS, BATCH), 256, 0, stream>>>(q_h, k_h, v_t, ao);
    gemm_out_kernel<<<dim3(DIM / 64, ROWS / 128), 256, 0, stream>>>(ao, Wt_o, bout, out);
}

// Round 7
// 235.900 us; speedup vs baseline: 1.6641x; 1.6641x over previous
//
#include <hip/hip_runtime.h>

#define HEADS 16
#define DHEAD 64
#define BATCH 2
#define SEQ   2048
#define DIM   1024
#define ROWS  (BATCH*SEQ)      // 4096
#define SCALE_LOG2E 0.180336880f   // 0.125 * log2(e)

typedef short v8s __attribute__((ext_vector_type(8)));
typedef float v4f __attribute__((ext_vector_type(4)));

__device__ __forceinline__ float fast_exp2(float x) {
    return __builtin_amdgcn_exp2f(x);   // v_exp_f32: D = 2^S0
}

__device__ __forceinline__ unsigned short f2bf(float f) {
    unsigned u = __float_as_uint(f);
    u += 0x7FFFu + ((u >> 16) & 1u);   // RNE
    return (unsigned short)(u >> 16);
}

// ---------------- LayerNorm: one block per row, bf16 out ----------------
__global__ __launch_bounds__(256) void ln_kernel(const float* __restrict__ x,
                                                 const float* __restrict__ gamma,
                                                 const float* __restrict__ beta,
                                                 unsigned short* __restrict__ xn) {
    int row = blockIdx.x;
    const float* xr = x + (size_t)row * DIM;
    int t = threadIdx.x;
    float4 v = *(const float4*)(xr + t * 4);
    float s  = v.x + v.y + v.z + v.w;
    float sq = v.x * v.x + v.y * v.y + v.z * v.z + v.w * v.w;
#pragma unroll
    for (int off = 32; off > 0; off >>= 1) {
        s  += __shfl_down(s,  off, 64);
        sq += __shfl_down(sq, off, 64);
    }
    __shared__ float ss[4], ssq[4];
    int wave = t >> 6, lane = t & 63;
    if (lane == 0) { ss[wave] = s; ssq[wave] = sq; }
    __syncthreads();
    float tot  = ss[0] + ss[1] + ss[2] + ss[3];
    float totq = ssq[0] + ssq[1] + ssq[2] + ssq[3];
    float mean = tot * (1.f / DIM);
    float var  = totq * (1.f / DIM) - mean * mean;
    float rstd = rsqrtf(var + 1e-5f);
    float4 g = *(const float4*)(gamma + t * 4);
    float4 bb = *(const float4*)(beta + t * 4);
    ushort4 o;
    o.x = f2bf((v.x - mean) * rstd * g.x + bb.x);
    o.y = f2bf((v.y - mean) * rstd * g.y + bb.y);
    o.z = f2bf((v.z - mean) * rstd * g.z + bb.z);
    o.w = f2bf((v.w - mean) * rstd * g.w + bb.w);
    *(ushort4*)(xn + (size_t)row * DIM + t * 4) = o;
}

// ---------------- Transpose + f32->bf16: Wt[n][k] = W[k][n] ----------------
__global__ __launch_bounds__(256) void tr_kernel(const float* __restrict__ W,
                                                 unsigned short* __restrict__ Wt,
                                                 int Kw, int Nw) {
    __shared__ float tile[64][65];
    int n0 = blockIdx.x * 64, k0 = blockIdx.y * 64;
    int tid = threadIdx.x;
#pragma unroll
    for (int l = 0; l < 4; ++l) {
        int kk = (tid >> 4) + l * 16;
        int nn = (tid & 15) * 4;
        float4 v = *(const float4*)(W + (size_t)(k0 + kk) * Nw + n0 + nn);
        tile[kk][nn + 0] = v.x; tile[kk][nn + 1] = v.y;
        tile[kk][nn + 2] = v.z; tile[kk][nn + 3] = v.w;
    }
    __syncthreads();
#pragma unroll
    for (int l = 0; l < 4; ++l) {
        int cid = tid + l * 256;
        int nn = cid >> 4, kc = (cid & 15) * 4;
        ushort4 o;
        o.x = f2bf(tile[kc + 0][nn]);
        o.y = f2bf(tile[kc + 1][nn]);
        o.z = f2bf(tile[kc + 2][nn]);
        o.w = f2bf(tile[kc + 3][nn]);
        *(ushort4*)(Wt + (size_t)(n0 + nn) * Kw + k0 + kc) = o;
    }
}

// ---------------- LDS-staged MFMA GEMM core ----------------
// BM=128, BK=32. BN=128: wave=64x64 (MI=4); BN=64: wave=32x64 (MI=2).
// LDS tiles padded to stride 40 shorts (80 B): uniform 2-way bank aliasing (free).
template<int BN>
__device__ __forceinline__ void mm_core2(const unsigned short* __restrict__ A,
                                         const unsigned short* __restrict__ Bt,
                                         int K, int aTile, int bTile,
                                         unsigned short (*As)[40],
                                         unsigned short (*Bs)[40],
                                         v4f (*acc)[4]) {
    constexpr int MI = (BN == 128) ? 4 : 2;
    int t = threadIdx.x;
    int w = t >> 6, L = t & 63, l15 = L & 15, quad = L >> 4;
    int aOff = (BN == 128) ? (w >> 1) * 64 : w * 32;
    int bOff = (BN == 128) ? (w & 1) * 64 : 0;
    for (int k0 = 0; k0 < K; k0 += 32) {
        __syncthreads();    // previous tile fully consumed
#pragma unroll
        for (int j = 0; j < 2; ++j) {
            int cid = t + j * 256;
            int row = cid >> 2, c = cid & 3;
            *(v8s*)&As[row][c * 8] =
                *(const v8s*)(A + (size_t)(aTile + row) * K + k0 + c * 8);
        }
#pragma unroll
        for (int j = 0; j < BN / 64; ++j) {
            int cid = t + j * 256;
            int row = cid >> 2, c = cid & 3;
            *(v8s*)&Bs[row][c * 8] =
                *(const v8s*)(Bt + (size_t)(bTile + row) * K + k0 + c * 8);
        }
        __syncthreads();    // tile visible
        v8s a[MI], b[4];
#pragma unroll
        for (int i = 0; i < MI; ++i) a[i] = *(const v8s*)&As[aOff + i * 16 + l15][quad * 8];
#pragma unroll
        for (int j = 0; j < 4; ++j) b[j] = *(const v8s*)&Bs[bOff + j * 16 + l15][quad * 8];
#pragma unroll
        for (int i = 0; i < MI; ++i)
#pragma unroll
            for (int j = 0; j < 4; ++j)
                acc[i][j] = __builtin_amdgcn_mfma_f32_16x16x32_bf16(a[i], b[j], acc[i][j], 0, 0, 0);
    }
}

// ---------------- GEMM -> q_h/k_h [b][h][seq][64] bf16 (BN=128) ----------------
__global__ __launch_bounds__(256) void gemm_qk_kernel(const unsigned short* __restrict__ A,
                                                      const unsigned short* __restrict__ Bt,
                                                      unsigned short* __restrict__ q_h,
                                                      unsigned short* __restrict__ k_h) {
    __shared__ __align__(16) unsigned short As[128][40];
    __shared__ __align__(16) unsigned short Bs[128][40];
    int t = threadIdx.x, w = t >> 6, L = t & 63, l15 = L & 15, quad = L >> 4;
    int aTile = blockIdx.y * 128, bTile = blockIdx.x * 128;
    int aOff = (w >> 1) * 64, bOff = (w & 1) * 64;
    v4f acc[4][4] = {};
    mm_core2<128>(A, Bt, DIM, aTile, bTile, As, Bs, acc);
#pragma unroll
    for (int j = 0; j < 4; ++j) {
        int col = bTile + bOff + j * 16 + l15;
        unsigned short* dst = (col < 1024) ? q_h : k_h;
        int c = col & 1023;
        int h = c >> 6, d = c & 63;
#pragma unroll
        for (int i = 0; i < 4; ++i) {
#pragma unroll
            for (int r = 0; r < 4; ++r) {
                int m = aTile + aOff + i * 16 + quad * 4 + r;
                int b = m >> 11, seq = m & 2047;
                dst[(((size_t)(b * 16 + h)) * SEQ + seq) * 64 + d] = f2bf(acc[i][j][r]);
            }
        }
    }
}

// ---------------- GEMM -> v_t [b][h][64][seq] bf16 transposed (BN=64) ----------------
__global__ __launch_bounds__(256) void gemm_v_kernel(const unsigned short* __restrict__ A,
                                                     const unsigned short* __restrict__ Bt,
                                                     unsigned short* __restrict__ v_t) {
    __shared__ __align__(16) unsigned short As[128][40];
    __shared__ __align__(16) unsigned short Bs[64][40];
    int t = threadIdx.x, w = t >> 6, L = t & 63, l15 = L & 15, quad = L >> 4;
    int aTile = blockIdx.y * 128, bTile = blockIdx.x * 64;
    v4f acc[2][4] = {};
    mm_core2<64>(A, Bt, DIM, aTile, bTile, As, Bs, acc);
#pragma unroll
    for (int j = 0; j < 4; ++j) {
        int c = bTile + j * 16 + l15;
        int h = c >> 6, d = c & 63;
#pragma unroll
        for (int i = 0; i < 2; ++i) {
            int m0 = aTile + w * 32 + i * 16 + quad * 4;
            int b = m0 >> 11, seq0 = m0 & 2047;
            ushort4 o;
            o.x = f2bf(acc[i][j][0]); o.y = f2bf(acc[i][j][1]);
            o.z = f2bf(acc[i][j][2]); o.w = f2bf(acc[i][j][3]);
            *(ushort4*)(v_t + (((size_t)(b * 16 + h)) * 64 + d) * SEQ + seq0) = o;
        }
    }
}

// ---------------- Final GEMM + bias, f32 out (BN=64) ----------------
__global__ __launch_bounds__(256) void gemm_out_kernel(const unsigned short* __restrict__ A,
                                                       const unsigned short* __restrict__ Bt,
                                                       const float* __restrict__ bias,
                                                       float* __restrict__ C) {
    __shared__ __align__(16) unsigned short As[128][40];
    __shared__ __align__(16) unsigned short Bs[64][40];
    int t = threadIdx.x, w = t >> 6, L = t & 63, l15 = L & 15, quad = L >> 4;
    int aTile = blockIdx.y * 128, bTile = blockIdx.x * 64;
    v4f acc[2][4] = {};
    mm_core2<64>(A, Bt, DIM, aTile, bTile, As, Bs, acc);
#pragma unroll
    for (int j = 0; j < 4; ++j) {
        int col = bTile + j * 16 + l15;
        float bv = bias[col];
#pragma unroll
        for (int i = 0; i < 2; ++i)
#pragma unroll
            for (int r = 0; r < 4; ++r) {
                int m = aTile + w * 32 + i * 16 + quad * 4 + r;
                C[(size_t)m * DIM + col] = acc[i][j][r] + bv;
            }
    }
}

// ---------------- MFMA flash attention, block-level K/V LDS staging ----------------
// block = 128 Q rows, 4 waves x 32 Q rows; 64 keys/iter staged once per BLOCK.
// Wave w stages key-tile jt=w (K) and d-tile dt=w (V) in fragment-lane order:
// slot (cb = jt*2+p, lane) holds row jt*16+(lane&15), shorts p*32+(lane>>4)*8.
// Both ds_write_b128 and ds_read_b128 are then stride-1 16B/lane: conflict-free.
__global__ __launch_bounds__(256) void attn_kernel(const unsigned short* __restrict__ q_h,
                                                   const unsigned short* __restrict__ k_h,
                                                   const unsigned short* __restrict__ v_t,
                                                   unsigned short* __restrict__ ao) {
    __shared__ __align__(16) unsigned short KF[8 * 64 * 8];   // 8 KB
    __shared__ __align__(16) unsigned short VF[8 * 64 * 8];   // 8 KB
    __shared__ __align__(16) unsigned short Pld[4][2][16 * 72]; // 18 KB
    int qt = blockIdx.x, h = blockIdx.y, b = blockIdx.z;
    int bh = b * HEADS + h;
    int w = threadIdx.x >> 6;
    int L = threadIdx.x & 63, l15 = L & 15, quad = L >> 4;
    int qrow0 = qt * 128 + w * 32;

    const unsigned short* qp = q_h + ((size_t)bh * SEQ + qrow0 + l15) * 64 + quad * 8;
    v8s qf[2][2];
    qf[0][0] = *(const v8s*)(qp);
    qf[0][1] = *(const v8s*)(qp + 32);
    qf[1][0] = *(const v8s*)(qp + 16 * 64);
    qf[1][1] = *(const v8s*)(qp + 16 * 64 + 32);

    // staging sources: wave w covers K rows w*16+l15, V d-rows w*16+l15
    const unsigned short* kstage = k_h + ((size_t)bh * SEQ + w * 16 + l15) * 64 + quad * 8;
    const unsigned short* vstage = v_t + ((size_t)bh * 64 + w * 16 + l15) * SEQ + quad * 8;

    v4f o[2][4] = {};
    float lsum[2][4] = {};

    for (int j0 = 0; j0 < SEQ; j0 += 64) {
        // ---- cooperative stage: global -> regs -> LDS (fragment order) ----
        v8s ks0 = *(const v8s*)(kstage + (size_t)j0 * 64);
        v8s ks1 = *(const v8s*)(kstage + (size_t)j0 * 64 + 32);
        v8s vs0 = *(const v8s*)(vstage + j0);
        v8s vs1 = *(const v8s*)(vstage + j0 + 32);
        __syncthreads();   // previous tile fully consumed
        *(v8s*)&KF[((w * 2 + 0) * 64 + L) * 8] = ks0;
        *(v8s*)&KF[((w * 2 + 1) * 64 + L) * 8] = ks1;
        *(v8s*)&VF[((w * 2 + 0) * 64 + L) * 8] = vs0;
        *(v8s*)&VF[((w * 2 + 1) * 64 + L) * 8] = vs1;
        __syncthreads();   // staged tile visible
        // ---- fragments from LDS ----
        v8s kf[4][2], vf[4][2];
#pragma unroll
        for (int jt = 0; jt < 4; ++jt) {
            kf[jt][0] = *(const v8s*)&KF[((jt * 2 + 0) * 64 + L) * 8];
            kf[jt][1] = *(const v8s*)&KF[((jt * 2 + 1) * 64 + L) * 8];
            vf[jt][0] = *(const v8s*)&VF[((jt * 2 + 0) * 64 + L) * 8];
            vf[jt][1] = *(const v8s*)&VF[((jt * 2 + 1) * 64 + L) * 8];
        }
        // ---- S = Q K^T ----
        v4f s[2][4] = {};
#pragma unroll
        for (int m = 0; m < 2; ++m)
#pragma unroll
            for (int jt = 0; jt < 4; ++jt) {
                s[m][jt] = __builtin_amdgcn_mfma_f32_16x16x32_bf16(qf[m][0], kf[jt][0], s[m][jt], 0, 0, 0);
                s[m][jt] = __builtin_amdgcn_mfma_f32_16x16x32_bf16(qf[m][1], kf[jt][1], s[m][jt], 0, 0, 0);
            }
        // ---- P = exp(S), per-lane l accumulation, C-layout -> LDS ----
#pragma unroll
        for (int m = 0; m < 2; ++m) {
#pragma unroll
            for (int r = 0; r < 4; ++r) {
                float p0 = fast_exp2(s[m][0][r] * SCALE_LOG2E);
                float p1 = fast_exp2(s[m][1][r] * SCALE_LOG2E);
                float p2 = fast_exp2(s[m][2][r] * SCALE_LOG2E);
                float p3 = fast_exp2(s[m][3][r] * SCALE_LOG2E);
                lsum[m][r] += (p0 + p1) + (p2 + p3);
                int rb = (quad * 4 + r) * 72 + l15;
                Pld[w][m][rb]      = f2bf(p0);
                Pld[w][m][rb + 16] = f2bf(p1);
                Pld[w][m][rb + 32] = f2bf(p2);
                Pld[w][m][rb + 48] = f2bf(p3);
            }
        }
        // ---- P back as A-fragments (wave-private LDS, no barrier) ----
        v8s pa[2][2];
#pragma unroll
        for (int m = 0; m < 2; ++m) {
            pa[m][0] = *(const v8s*)(&Pld[w][m][l15 * 72 + quad * 8]);
            pa[m][1] = *(const v8s*)(&Pld[w][m][l15 * 72 + 32 + quad * 8]);
        }
        // ---- O += P V ----
#pragma unroll
        for (int m = 0; m < 2; ++m)
#pragma unroll
            for (int dt = 0; dt < 4; ++dt) {
                o[m][dt] = __builtin_amdgcn_mfma_f32_16x16x32_bf16(pa[m][0], vf[dt][0], o[m][dt], 0, 0, 0);
                o[m][dt] = __builtin_amdgcn_mfma_f32_16x16x32_bf16(pa[m][1], vf[dt][1], o[m][dt], 0, 0, 0);
            }
    }
    // ---- final row-sum reduction (within 16-lane group) + store ----
#pragma unroll
    for (int m = 0; m < 2; ++m)
#pragma unroll
        for (int r = 0; r < 4; ++r) {
            float sm = lsum[m][r];
            sm += __shfl_xor(sm, 1, 64);
            sm += __shfl_xor(sm, 2, 64);
            sm += __shfl_xor(sm, 4, 64);
            sm += __shfl_xor(sm, 8, 64);
            lsum[m][r] = 1.f / sm;
        }
#pragma unroll
    for (int m = 0; m < 2; ++m)
#pragma unroll
        for (int r = 0; r < 4; ++r) {
            int rowg = b * SEQ + qt * 128 + w * 32 + m * 16 + quad * 4 + r;
            size_t base = (size_t)rowg * DIM + h * 64 + l15;
            float inv = lsum[m][r];
            ao[base]      = f2bf(o[m][0][r] * inv);
            ao[base + 16] = f2bf(o[m][1][r] * inv);
            ao[base + 32] = f2bf(o[m][2][r] * inv);
            ao[base + 48] = f2bf(o[m][3][r] * inv);
        }
}

extern "C" void kernel_launch(void* const* d_in, const int* in_sizes, int n_in,
                              void* d_out, int out_size, void* d_ws, size_t ws_size,
                              hipStream_t stream) {
    const float* x     = (const float*)d_in[0];
    const float* gamma = (const float*)d_in[1];
    const float* beta  = (const float*)d_in[2];
    const float* Wqk   = (const float*)d_in[3];
    const float* Wv    = (const float*)d_in[4];
    const float* Wout  = (const float*)d_in[5];
    const float* bout  = (const float*)d_in[6];
    float* out = (float*)d_out;

    unsigned short* ws = (unsigned short*)d_ws;
    unsigned short* xn    = ws;                            // 4096*1024
    unsigned short* Wt_qk = xn + (size_t)ROWS * DIM;       // 2048*1024
    unsigned short* Wt_v  = Wt_qk + (size_t)2048 * DIM;    // 1024*1024
    unsigned short* Wt_o  = Wt_v + (size_t)DIM * DIM;      // 1024*1024
    unsigned short* q_h   = Wt_o + (size_t)DIM * DIM;      // 4096*1024
    unsigned short* k_h   = q_h + (size_t)ROWS * DIM;      // 4096*1024
    unsigned short* v_t   = k_h + (size_t)ROWS * DIM;      // 4096*1024
    unsigned short* ao    = v_t + (size_t)ROWS * DIM;      // 4096*1024

    ln_kernel<<<ROWS, 256, 0, stream>>>(x, gamma, beta, xn);
    tr_kernel<<<dim3(2048 / 64, DIM / 64), 256, 0, stream>>>(Wqk, Wt_qk, DIM, 2048);
    tr_kernel<<<dim3(DIM / 64, DIM / 64), 256, 0, stream>>>(Wv, Wt_v, DIM, DIM);
    tr_kernel<<<dim3(DIM / 64, DIM / 64), 256, 0, stream>>>(Wout, Wt_o, DIM, DIM);
    gemm_qk_kernel<<<dim3(2048 / 128, ROWS / 128), 256, 0, stream>>>(xn, Wt_qk, q_h, k_h);
    gemm_v_kernel<<<dim3(DIM / 64, ROWS / 128), 256, 0, stream>>>(xn, Wt_v, v_t);
    attn_kernel<<<dim3(SEQ / 128, HEADS, BATCH), 256, 0, stream>>>(q_h, k_h, v_t, ao);
    gemm_out_kernel<<<dim3(DIM / 64, ROWS / 128), 256, 0, stream>>>(ao, Wt_o, bout, out);
}

// Round 8
// 208.485 us; speedup vs baseline: 1.8829x; 1.1315x over previous
//
#include <hip/hip_runtime.h>

#define HEADS 16
#define DHEAD 64
#define BATCH 2
#define SEQ   2048
#define DIM   1024
#define ROWS  (BATCH*SEQ)      // 4096
#define SCALE_LOG2E 0.180336880f   // 0.125 * log2(e)

typedef short v8s __attribute__((ext_vector_type(8)));
typedef float v4f __attribute__((ext_vector_type(4)));

__device__ __forceinline__ float fast_exp2(float x) {
    return __builtin_amdgcn_exp2f(x);   // v_exp_f32: D = 2^S0
}

__device__ __forceinline__ unsigned short f2bf(float f) {
    unsigned u = __float_as_uint(f);
    u += 0x7FFFu + ((u >> 16) & 1u);   // RNE
    return (unsigned short)(u >> 16);
}

// pack two f32 -> bf16x2 dword (truncation): low short = bf(lo), high = bf(hi)
__device__ __forceinline__ unsigned pk_bf2(float hi, float lo) {
    return __builtin_amdgcn_perm(__float_as_uint(hi), __float_as_uint(lo), 0x07060302u);
}

// async global->LDS, 16B per lane
#define GLDS16(g, l) __builtin_amdgcn_global_load_lds( \
    (__attribute__((address_space(1))) void*)(g), \
    (__attribute__((address_space(3))) void*)(l), 16, 0, 0)

// ---------------- LayerNorm: one block per row, bf16 out ----------------
__global__ __launch_bounds__(256) void ln_kernel(const float* __restrict__ x,
                                                 const float* __restrict__ gamma,
                                                 const float* __restrict__ beta,
                                                 unsigned short* __restrict__ xn) {
    int row = blockIdx.x;
    const float* xr = x + (size_t)row * DIM;
    int t = threadIdx.x;
    float4 v = *(const float4*)(xr + t * 4);
    float s  = v.x + v.y + v.z + v.w;
    float sq = v.x * v.x + v.y * v.y + v.z * v.z + v.w * v.w;
#pragma unroll
    for (int off = 32; off > 0; off >>= 1) {
        s  += __shfl_down(s,  off, 64);
        sq += __shfl_down(sq, off, 64);
    }
    __shared__ float ss[4], ssq[4];
    int wave = t >> 6, lane = t & 63;
    if (lane == 0) { ss[wave] = s; ssq[wave] = sq; }
    __syncthreads();
    float tot  = ss[0] + ss[1] + ss[2] + ss[3];
    float totq = ssq[0] + ssq[1] + ssq[2] + ssq[3];
    float mean = tot * (1.f / DIM);
    float var  = totq * (1.f / DIM) - mean * mean;
    float rstd = rsqrtf(var + 1e-5f);
    float4 g = *(const float4*)(gamma + t * 4);
    float4 bb = *(const float4*)(beta + t * 4);
    ushort4 o;
    o.x = f2bf((v.x - mean) * rstd * g.x + bb.x);
    o.y = f2bf((v.y - mean) * rstd * g.y + bb.y);
    o.z = f2bf((v.z - mean) * rstd * g.z + bb.z);
    o.w = f2bf((v.w - mean) * rstd * g.w + bb.w);
    *(ushort4*)(xn + (size_t)row * DIM + t * 4) = o;
}

// ---------------- Transpose + f32->bf16: Wt[n][k] = W[k][n] ----------------
__global__ __launch_bounds__(256) void tr_kernel(const float* __restrict__ W,
                                                 unsigned short* __restrict__ Wt,
                                                 int Kw, int Nw) {
    __shared__ float tile[64][65];
    int n0 = blockIdx.x * 64, k0 = blockIdx.y * 64;
    int tid = threadIdx.x;
#pragma unroll
    for (int l = 0; l < 4; ++l) {
        int kk = (tid >> 4) + l * 16;
        int nn = (tid & 15) * 4;
        float4 v = *(const float4*)(W + (size_t)(k0 + kk) * Nw + n0 + nn);
        tile[kk][nn + 0] = v.x; tile[kk][nn + 1] = v.y;
        tile[kk][nn + 2] = v.z; tile[kk][nn + 3] = v.w;
    }
    __syncthreads();
#pragma unroll
    for (int l = 0; l < 4; ++l) {
        int cid = tid + l * 256;
        int nn = cid >> 4, kc = (cid & 15) * 4;
        ushort4 o;
        o.x = f2bf(tile[kc + 0][nn]);
        o.y = f2bf(tile[kc + 1][nn]);
        o.z = f2bf(tile[kc + 2][nn]);
        o.w = f2bf(tile[kc + 3][nn]);
        *(ushort4*)(Wt + (size_t)(n0 + nn) * Kw + k0 + kc) = o;
    }
}

// ---------------- LDS-staged MFMA GEMM core with global_load_lds ----------------
// BM=128, BK=32. LDS unpadded [rows][32] shorts (64B rows) so lane*16B is linear.
// BN=128: wave=64x64 (MI=4); BN=64: wave=32x64 (MI=2).
template<int BN>
__device__ __forceinline__ void mm_core2(const unsigned short* __restrict__ A,
                                         const unsigned short* __restrict__ Bt,
                                         int K, int aTile, int bTile,
                                         unsigned short (*As)[32],
                                         unsigned short (*Bs)[32],
                                         v4f (*acc)[4]) {
    constexpr int MI = (BN == 128) ? 4 : 2;
    int t = threadIdx.x;
    int w = t >> 6, L = t & 63, l15 = L & 15, quad = L >> 4;
    int aOff = (BN == 128) ? (w >> 1) * 64 : w * 32;
    int bOff = (BN == 128) ? (w & 1) * 64 : 0;
    int srow = L >> 2, schunk = (L & 3) * 8;   // staging: 4 lanes per row
    for (int k0 = 0; k0 < K; k0 += 32) {
        __syncthreads();    // previous tile fully consumed
        // stage A: 128 rows, 8 groups of 16 rows; wave w does groups w*2, w*2+1
#pragma unroll
        for (int j = 0; j < 2; ++j) {
            int g = w * 2 + j;
            GLDS16(A + (size_t)(aTile + g * 16 + srow) * K + k0 + schunk,
                   &As[g * 16][0]);
        }
        // stage B: BN rows
#pragma unroll
        for (int j = 0; j < BN / 64; ++j) {
            int g = (BN == 128) ? (w * 2 + j) : w;
            GLDS16(Bt + (size_t)(bTile + g * 16 + srow) * K + k0 + schunk,
                   &Bs[g * 16][0]);
        }
        __syncthreads();    // drains vmcnt: staged tile visible
        v8s a[MI], b[4];
#pragma unroll
        for (int i = 0; i < MI; ++i) a[i] = *(const v8s*)&As[aOff + i * 16 + l15][quad * 8];
#pragma unroll
        for (int j = 0; j < 4; ++j) b[j] = *(const v8s*)&Bs[bOff + j * 16 + l15][quad * 8];
#pragma unroll
        for (int i = 0; i < MI; ++i)
#pragma unroll
            for (int j = 0; j < 4; ++j)
                acc[i][j] = __builtin_amdgcn_mfma_f32_16x16x32_bf16(a[i], b[j], acc[i][j], 0, 0, 0);
    }
}

// ---------------- GEMM -> q_h/k_h [b][h][seq][64] bf16 (BN=128) ----------------
__global__ __launch_bounds__(256) void gemm_qk_kernel(const unsigned short* __restrict__ A,
                                                      const unsigned short* __restrict__ Bt,
                                                      unsigned short* __restrict__ q_h,
                                                      unsigned short* __restrict__ k_h) {
    __shared__ __align__(16) unsigned short As[128][32];
    __shared__ __align__(16) unsigned short Bs[128][32];
    int t = threadIdx.x, w = t >> 6, L = t & 63, l15 = L & 15, quad = L >> 4;
    int aTile = blockIdx.y * 128, bTile = blockIdx.x * 128;
    int aOff = (w >> 1) * 64, bOff = (w & 1) * 64;
    v4f acc[4][4] = {};
    mm_core2<128>(A, Bt, DIM, aTile, bTile, As, Bs, acc);
#pragma unroll
    for (int j = 0; j < 4; ++j) {
        int col = bTile + bOff + j * 16 + l15;
        unsigned short* dst = (col < 1024) ? q_h : k_h;
        int c = col & 1023;
        int h = c >> 6, d = c & 63;
#pragma unroll
        for (int i = 0; i < 4; ++i) {
#pragma unroll
            for (int r = 0; r < 4; ++r) {
                int m = aTile + aOff + i * 16 + quad * 4 + r;
                int b = m >> 11, seq = m & 2047;
                dst[(((size_t)(b * 16 + h)) * SEQ + seq) * 64 + d] = f2bf(acc[i][j][r]);
            }
        }
    }
}

// ---------------- GEMM -> v_t [b][h][64][seq] bf16 transposed (BN=64) ----------------
__global__ __launch_bounds__(256) void gemm_v_kernel(const unsigned short* __restrict__ A,
                                                     const unsigned short* __restrict__ Bt,
                                                     unsigned short* __restrict__ v_t) {
    __shared__ __align__(16) unsigned short As[128][32];
    __shared__ __align__(16) unsigned short Bs[64][32];
    int t = threadIdx.x, w = t >> 6, L = t & 63, l15 = L & 15, quad = L >> 4;
    int aTile = blockIdx.y * 128, bTile = blockIdx.x * 64;
    v4f acc[2][4] = {};
    mm_core2<64>(A, Bt, DIM, aTile, bTile, As, Bs, acc);
#pragma unroll
    for (int j = 0; j < 4; ++j) {
        int c = bTile + j * 16 + l15;
        int h = c >> 6, d = c & 63;
#pragma unroll
        for (int i = 0; i < 2; ++i) {
            int m0 = aTile + w * 32 + i * 16 + quad * 4;
            int b = m0 >> 11, seq0 = m0 & 2047;
            ushort4 o;
            o.x = f2bf(acc[i][j][0]); o.y = f2bf(acc[i][j][1]);
            o.z = f2bf(acc[i][j][2]); o.w = f2bf(acc[i][j][3]);
            *(ushort4*)(v_t + (((size_t)(b * 16 + h)) * 64 + d) * SEQ + seq0) = o;
        }
    }
}

// ---------------- Final GEMM + bias, f32 out (BN=64) ----------------
__global__ __launch_bounds__(256) void gemm_out_kernel(const unsigned short* __restrict__ A,
                                                       const unsigned short* __restrict__ Bt,
                                                       const float* __restrict__ bias,
                                                       float* __restrict__ C) {
    __shared__ __align__(16) unsigned short As[128][32];
    __shared__ __align__(16) unsigned short Bs[64][32];
    int t = threadIdx.x, w = t >> 6, L = t & 63, l15 = L & 15, quad = L >> 4;
    int aTile = blockIdx.y * 128, bTile = blockIdx.x * 64;
    v4f acc[2][4] = {};
    mm_core2<64>(A, Bt, DIM, aTile, bTile, As, Bs, acc);
#pragma unroll
    for (int j = 0; j < 4; ++j) {
        int col = bTile + j * 16 + l15;
        float bv = bias[col];
#pragma unroll
        for (int i = 0; i < 2; ++i)
#pragma unroll
            for (int r = 0; r < 4; ++r) {
                int m = aTile + w * 32 + i * 16 + quad * 4 + r;
                C[(size_t)m * DIM + col] = acc[i][j][r] + bv;
            }
    }
}

// ---------------- MFMA flash attention (S^T formulation) ----------------
// block = 128 Q rows, 4 waves x 32 Q rows; 64 keys/iter staged once per block.
// s_T = mfma(K_frag, Q_frag): C gives qrow=l15, key=quad*4+r  ->  lane's 4 P
// values consecutive in key: pack 2x bf16 via v_perm, ds_write_b64.
// PV as O^T = mfma(V_frag, P^T_frag); lsum via ones-MFMA (consistent with P~).
__global__ __launch_bounds__(256) void attn_kernel(const unsigned short* __restrict__ q_h,
                                                   const unsigned short* __restrict__ k_h,
                                                   const unsigned short* __restrict__ v_t,
                                                   unsigned short* __restrict__ ao) {
    __shared__ __align__(16) unsigned short KF[8 * 64 * 8];     // 8 KB
    __shared__ __align__(16) unsigned short VF[8 * 64 * 8];     // 8 KB
    __shared__ __align__(16) unsigned short Pld[4][2][16 * 72]; // 18 KB
    int qt = blockIdx.x, h = blockIdx.y, b = blockIdx.z;
    int bh = b * HEADS + h;
    int w = threadIdx.x >> 6;
    int L = threadIdx.x & 63, l15 = L & 15, quad = L >> 4;

    // Q as B-operand: B[k=d][n=qrow]: row = base + l15, d = p*32 + quad*8
    const unsigned short* qp = q_h + ((size_t)bh * SEQ + qt * 128 + w * 32 + l15) * 64 + quad * 8;
    v8s qf[2][2];
    qf[0][0] = *(const v8s*)(qp);
    qf[0][1] = *(const v8s*)(qp + 32);
    qf[1][0] = *(const v8s*)(qp + 16 * 64);
    qf[1][1] = *(const v8s*)(qp + 16 * 64 + 32);

    const unsigned short* kstage = k_h + ((size_t)bh * SEQ + w * 16 + l15) * 64 + quad * 8;
    const unsigned short* vstage = v_t + ((size_t)bh * 64 + w * 16 + l15) * SEQ + quad * 8;

    v4f o[2][4] = {};
    v4f lacc[2] = {};
    const short ob = (short)0x3F80;   // bf16 1.0
    const v8s ones = {ob, ob, ob, ob, ob, ob, ob, ob};

    // prefetch first K/V tile
    v8s ks0 = *(const v8s*)(kstage);
    v8s ks1 = *(const v8s*)(kstage + 32);
    v8s vs0 = *(const v8s*)(vstage);
    v8s vs1 = *(const v8s*)(vstage + 32);

    for (int j0 = 0; j0 < SEQ; j0 += 64) {
        __syncthreads();   // previous tile fully consumed
        *(v8s*)&KF[((w * 2 + 0) * 64 + L) * 8] = ks0;
        *(v8s*)&KF[((w * 2 + 1) * 64 + L) * 8] = ks1;
        *(v8s*)&VF[((w * 2 + 0) * 64 + L) * 8] = vs0;
        *(v8s*)&VF[((w * 2 + 1) * 64 + L) * 8] = vs1;
        __syncthreads();   // staged tile visible
        // prefetch next tile (latency hidden behind MFMA/exp below)
        if (j0 + 64 < SEQ) {
            ks0 = *(const v8s*)(kstage + (size_t)(j0 + 64) * 64);
            ks1 = *(const v8s*)(kstage + (size_t)(j0 + 64) * 64 + 32);
            vs0 = *(const v8s*)(vstage + j0 + 64);
            vs1 = *(const v8s*)(vstage + j0 + 64 + 32);
        }
        // fragments from LDS
        v8s kf[4][2], vf[4][2];
#pragma unroll
        for (int jt = 0; jt < 4; ++jt) {
            kf[jt][0] = *(const v8s*)&KF[((jt * 2 + 0) * 64 + L) * 8];
            kf[jt][1] = *(const v8s*)&KF[((jt * 2 + 1) * 64 + L) * 8];
            vf[jt][0] = *(const v8s*)&VF[((jt * 2 + 0) * 64 + L) * 8];
            vf[jt][1] = *(const v8s*)&VF[((jt * 2 + 1) * 64 + L) * 8];
        }
        // S^T = K Q^T : per (m,jt) tile 16key x 16qrow
        v4f s[2][4] = {};
#pragma unroll
        for (int m = 0; m < 2; ++m)
#pragma unroll
            for (int jt = 0; jt < 4; ++jt) {
                s[m][jt] = __builtin_amdgcn_mfma_f32_16x16x32_bf16(kf[jt][0], qf[m][0], s[m][jt], 0, 0, 0);
                s[m][jt] = __builtin_amdgcn_mfma_f32_16x16x32_bf16(kf[jt][1], qf[m][1], s[m][jt], 0, 0, 0);
            }
        // P = exp(S^T), packed bf16x2, one b64 write per (m,jt)
#pragma unroll
        for (int m = 0; m < 2; ++m)
#pragma unroll
            for (int jt = 0; jt < 4; ++jt) {
                float p0 = fast_exp2(s[m][jt][0] * SCALE_LOG2E);
                float p1 = fast_exp2(s[m][jt][1] * SCALE_LOG2E);
                float p2 = fast_exp2(s[m][jt][2] * SCALE_LOG2E);
                float p3 = fast_exp2(s[m][jt][3] * SCALE_LOG2E);
                uint2 pk;
                pk.x = pk_bf2(p1, p0);
                pk.y = pk_bf2(p3, p2);
                *(uint2*)&Pld[w][m][l15 * 72 + jt * 16 + quad * 4] = pk;
            }
        // P^T as B-operand; O^T += V P^T ; lsum via ones-MFMA
#pragma unroll
        for (int m = 0; m < 2; ++m) {
            v8s pb0 = *(const v8s*)&Pld[w][m][l15 * 72 + quad * 8];
            v8s pb1 = *(const v8s*)&Pld[w][m][l15 * 72 + 32 + quad * 8];
#pragma unroll
            for (int dt = 0; dt < 4; ++dt) {
                o[m][dt] = __builtin_amdgcn_mfma_f32_16x16x32_bf16(vf[dt][0], pb0, o[m][dt], 0, 0, 0);
                o[m][dt] = __builtin_amdgcn_mfma_f32_16x16x32_bf16(vf[dt][1], pb1, o[m][dt], 0, 0, 0);
            }
            lacc[m] = __builtin_amdgcn_mfma_f32_16x16x32_bf16(ones, pb0, lacc[m], 0, 0, 0);
            lacc[m] = __builtin_amdgcn_mfma_f32_16x16x32_bf16(ones, pb1, lacc[m], 0, 0, 0);
        }
    }
    // normalize + store: lane has qrow=l15, d = dt*16 + quad*4 + r
#pragma unroll
    for (int m = 0; m < 2; ++m) {
        float inv = 1.f / lacc[m][0];
        int rowg = b * SEQ + qt * 128 + w * 32 + m * 16 + l15;
#pragma unroll
        for (int dt = 0; dt < 4; ++dt) {
            ushort4 ov;
            ov.x = f2bf(o[m][dt][0] * inv);
            ov.y = f2bf(o[m][dt][1] * inv);
            ov.z = f2bf(o[m][dt][2] * inv);
            ov.w = f2bf(o[m][dt][3] * inv);
            *(ushort4*)(ao + (size_t)rowg * DIM + h * 64 + dt * 16 + quad * 4) = ov;
        }
    }
}

extern "C" void kernel_launch(void* const* d_in, const int* in_sizes, int n_in,
                              void* d_out, int out_size, void* d_ws, size_t ws_size,
                              hipStream_t stream) {
    const float* x     = (const float*)d_in[0];
    const float* gamma = (const float*)d_in[1];
    const float* beta  = (const float*)d_in[2];
    const float* Wqk   = (const float*)d_in[3];
    const float* Wv    = (const float*)d_in[4];
    const float* Wout  = (const float*)d_in[5];
    const float* bout  = (const float*)d_in[6];
    float* out = (float*)d_out;

    unsigned short* ws = (unsigned short*)d_ws;
    unsigned short* xn    = ws;                            // 4096*1024
    unsigned short* Wt_qk = xn + (size_t)ROWS * DIM;       // 2048*1024
    unsigned short* Wt_v  = Wt_qk + (size_t)2048 * DIM;    // 1024*1024
    unsigned short* Wt_o  = Wt_v + (size_t)DIM * DIM;      // 1024*1024
    unsigned short* q_h   = Wt_o + (size_t)DIM * DIM;      // 4096*1024
    unsigned short* k_h   = q_h + (size_t)ROWS * DIM;      // 4096*1024
    unsigned short* v_t   = k_h + (size_t)ROWS * DIM;      // 4096*1024
    unsigned short* ao    = v_t + (size_t)ROWS * DIM;      // 4096*1024

    ln_kernel<<<ROWS, 256, 0, stream>>>(x, gamma, beta, xn);
    tr_kernel<<<dim3(2048 / 64, DIM / 64), 256, 0, stream>>>(Wqk, Wt_qk, DIM, 2048);
    tr_kernel<<<dim3(DIM / 64, DIM / 64), 256, 0, stream>>>(Wv, Wt_v, DIM, DIM);
    tr_kernel<<<dim3(DIM / 64, DIM / 64), 256, 0, stream>>>(Wout, Wt_o, DIM, DIM);
    gemm_qk_kernel<<<dim3(2048 / 128, ROWS / 128), 256, 0, stream>>>(xn, Wt_qk, q_h, k_h);
    gemm_v_kernel<<<dim3(DIM / 64, ROWS / 128), 256, 0, stream>>>(xn, Wt_v, v_t);
    attn_kernel<<<dim3(SEQ / 128, HEADS, BATCH), 256, 0, stream>>>(q_h, k_h, v_t, ao);
    gemm_out_kernel<<<dim3(DIM / 64, ROWS / 128), 256, 0, stream>>>(ao, Wt_o, bout, out);
}

// Round 9
// 194.892 us; speedup vs baseline: 2.0143x; 1.0697x over previous
//
#include <hip/hip_runtime.h>

#define HEADS 16
#define DHEAD 64
#define BATCH 2
#define SEQ   2048
#define DIM   1024
#define ROWS  (BATCH*SEQ)      // 4096
#define SCALE_LOG2E 0.180336880f   // 0.125 * log2(e)

typedef short v8s __attribute__((ext_vector_type(8)));
typedef float v4f __attribute__((ext_vector_type(4)));

__device__ __forceinline__ float fast_exp2(float x) {
    return __builtin_amdgcn_exp2f(x);   // v_exp_f32: D = 2^S0
}

__device__ __forceinline__ unsigned short f2bf(float f) {
    unsigned u = __float_as_uint(f);
    u += 0x7FFFu + ((u >> 16) & 1u);   // RNE
    return (unsigned short)(u >> 16);
}

// pack two f32 -> bf16x2 dword (truncation): low short = bf(lo), high = bf(hi)
__device__ __forceinline__ unsigned pk_bf2(float hi, float lo) {
    return __builtin_amdgcn_perm(__float_as_uint(hi), __float_as_uint(lo), 0x07060302u);
}

// async global->LDS, 16B per lane
#define GLDS16(g, l) __builtin_amdgcn_global_load_lds( \
    (__attribute__((address_space(1))) void*)(g), \
    (__attribute__((address_space(3))) void*)(l), 16, 0, 0)

// ---------------- LayerNorm: one block per row, bf16 out ----------------
__global__ __launch_bounds__(256) void ln_kernel(const float* __restrict__ x,
                                                 const float* __restrict__ gamma,
                                                 const float* __restrict__ beta,
                                                 unsigned short* __restrict__ xn) {
    int row = blockIdx.x;
    const float* xr = x + (size_t)row * DIM;
    int t = threadIdx.x;
    float4 v = *(const float4*)(xr + t * 4);
    float s  = v.x + v.y + v.z + v.w;
    float sq = v.x * v.x + v.y * v.y + v.z * v.z + v.w * v.w;
#pragma unroll
    for (int off = 32; off > 0; off >>= 1) {
        s  += __shfl_down(s,  off, 64);
        sq += __shfl_down(sq, off, 64);
    }
    __shared__ float ss[4], ssq[4];
    int wave = t >> 6, lane = t & 63;
    if (lane == 0) { ss[wave] = s; ssq[wave] = sq; }
    __syncthreads();
    float tot  = ss[0] + ss[1] + ss[2] + ss[3];
    float totq = ssq[0] + ssq[1] + ssq[2] + ssq[3];
    float mean = tot * (1.f / DIM);
    float var  = totq * (1.f / DIM) - mean * mean;
    float rstd = rsqrtf(var + 1e-5f);
    float4 g = *(const float4*)(gamma + t * 4);
    float4 bb = *(const float4*)(beta + t * 4);
    ushort4 o;
    o.x = f2bf((v.x - mean) * rstd * g.x + bb.x);
    o.y = f2bf((v.y - mean) * rstd * g.y + bb.y);
    o.z = f2bf((v.z - mean) * rstd * g.z + bb.z);
    o.w = f2bf((v.w - mean) * rstd * g.w + bb.w);
    *(ushort4*)(xn + (size_t)row * DIM + t * 4) = o;
}

// ---------------- Fused transpose + f32->bf16 for all 3 weights ----------------
// z=0: Wqk (1024x2048), z=1: Wv (1024x1024), z=2: Wout (1024x1024)
__global__ __launch_bounds__(256) void tr_all_kernel(const float* __restrict__ Wqk,
                                                     const float* __restrict__ Wv,
                                                     const float* __restrict__ Wout,
                                                     unsigned short* __restrict__ Tqk,
                                                     unsigned short* __restrict__ Tv,
                                                     unsigned short* __restrict__ To) {
    int z = blockIdx.z;
    const float* W = (z == 0) ? Wqk : (z == 1) ? Wv : Wout;
    unsigned short* Wt = (z == 0) ? Tqk : (z == 1) ? Tv : To;
    int Nw = (z == 0) ? 2048 : 1024;
    int n0 = blockIdx.x * 64, k0 = blockIdx.y * 64;
    if (n0 >= Nw) return;
    __shared__ float tile[64][65];
    int tid = threadIdx.x;
#pragma unroll
    for (int l = 0; l < 4; ++l) {
        int kk = (tid >> 4) + l * 16;
        int nn = (tid & 15) * 4;
        float4 v = *(const float4*)(W + (size_t)(k0 + kk) * Nw + n0 + nn);
        tile[kk][nn + 0] = v.x; tile[kk][nn + 1] = v.y;
        tile[kk][nn + 2] = v.z; tile[kk][nn + 3] = v.w;
    }
    __syncthreads();
#pragma unroll
    for (int l = 0; l < 4; ++l) {
        int cid = tid + l * 256;
        int nn = cid >> 4, kc = (cid & 15) * 4;
        ushort4 o;
        o.x = f2bf(tile[kc + 0][nn]);
        o.y = f2bf(tile[kc + 1][nn]);
        o.z = f2bf(tile[kc + 2][nn]);
        o.w = f2bf(tile[kc + 3][nn]);
        *(ushort4*)(Wt + (size_t)(n0 + nn) * DIM + k0 + kc) = o;
    }
}

// ---------------- LDS-staged MFMA GEMM core with global_load_lds ----------------
// BM=128, BK=32. LDS unpadded [rows][32] shorts (64B rows) so lane*16B is linear.
// BN=128: wave=64x64 (MI=4); BN=64: wave=32x64 (MI=2).
// SWAP: acc[i][j] = mfma(b[j], a[i]) -> C^T layout: lane m=l15, 4 consecutive n.
template<int BN, bool SWAP>
__device__ __forceinline__ void mm_core2(const unsigned short* __restrict__ A,
                                         const unsigned short* __restrict__ Bt,
                                         int K, int aTile, int bTile,
                                         unsigned short (*As)[32],
                                         unsigned short (*Bs)[32],
                                         v4f (*acc)[4]) {
    constexpr int MI = (BN == 128) ? 4 : 2;
    int t = threadIdx.x;
    int w = t >> 6, L = t & 63, l15 = L & 15, quad = L >> 4;
    int aOff = (BN == 128) ? (w >> 1) * 64 : w * 32;
    int bOff = (BN == 128) ? (w & 1) * 64 : 0;
    int srow = L >> 2, schunk = (L & 3) * 8;   // staging: 4 lanes per row
    for (int k0 = 0; k0 < K; k0 += 32) {
        __syncthreads();    // previous tile fully consumed
#pragma unroll
        for (int j = 0; j < 2; ++j) {
            int g = w * 2 + j;
            GLDS16(A + (size_t)(aTile + g * 16 + srow) * K + k0 + schunk,
                   &As[g * 16][0]);
        }
#pragma unroll
        for (int j = 0; j < BN / 64; ++j) {
            int g = (BN == 128) ? (w * 2 + j) : w;
            GLDS16(Bt + (size_t)(bTile + g * 16 + srow) * K + k0 + schunk,
                   &Bs[g * 16][0]);
        }
        __syncthreads();    // drains vmcnt: staged tile visible
        v8s a[MI], b[4];
#pragma unroll
        for (int i = 0; i < MI; ++i) a[i] = *(const v8s*)&As[aOff + i * 16 + l15][quad * 8];
#pragma unroll
        for (int j = 0; j < 4; ++j) b[j] = *(const v8s*)&Bs[bOff + j * 16 + l15][quad * 8];
#pragma unroll
        for (int i = 0; i < MI; ++i)
#pragma unroll
            for (int j = 0; j < 4; ++j)
                acc[i][j] = SWAP
                    ? __builtin_amdgcn_mfma_f32_16x16x32_bf16(b[j], a[i], acc[i][j], 0, 0, 0)
                    : __builtin_amdgcn_mfma_f32_16x16x32_bf16(a[i], b[j], acc[i][j], 0, 0, 0);
    }
}

// ---------------- Fused GEMM -> q_h/k_h [b][h][seq][64] + v_t [b][h][64][seq] ----
// N = 3072 (Wt_qk rows 0..2047, Wt_v rows 2048..3071 contiguous in workspace).
// q/k tiles: SWAP (C^T) -> lane holds 4 consecutive d -> ushort4 stores.
// v tiles: normal C -> 4 consecutive seq -> ushort4 stores into transposed v_t.
__global__ __launch_bounds__(256) void gemm_qkv_kernel(const unsigned short* __restrict__ A,
                                                       const unsigned short* __restrict__ Bt,
                                                       unsigned short* __restrict__ q_h,
                                                       unsigned short* __restrict__ k_h,
                                                       unsigned short* __restrict__ v_t) {
    __shared__ __align__(16) unsigned short As[128][32];
    __shared__ __align__(16) unsigned short Bs[128][32];
    int t = threadIdx.x, w = t >> 6, L = t & 63, l15 = L & 15, quad = L >> 4;
    int aTile = blockIdx.y * 128, bTile = blockIdx.x * 128;
    int aOff = (w >> 1) * 64, bOff = (w & 1) * 64;
    v4f acc[4][4] = {};
    if (bTile < 2048) {
        mm_core2<128, true>(A, Bt, DIM, aTile, bTile, As, Bs, acc);
#pragma unroll
        for (int j = 0; j < 4; ++j) {
            int col = bTile + bOff + j * 16 + quad * 4;   // 4 consecutive
            unsigned short* dst = (col < 1024) ? q_h : k_h;
            int c = col & 1023;
            int h = c >> 6, d = c & 63;
#pragma unroll
            for (int i = 0; i < 4; ++i) {
                int m = aTile + aOff + i * 16 + l15;
                int b = m >> 11, seq = m & 2047;
                ushort4 o;
                o.x = f2bf(acc[i][j][0]); o.y = f2bf(acc[i][j][1]);
                o.z = f2bf(acc[i][j][2]); o.w = f2bf(acc[i][j][3]);
                *(ushort4*)(dst + (((size_t)(b * 16 + h)) * SEQ + seq) * 64 + d) = o;
            }
        }
    } else {
        mm_core2<128, false>(A, Bt, DIM, aTile, bTile, As, Bs, acc);
#pragma unroll
        for (int j = 0; j < 4; ++j) {
            int c = bTile + bOff + j * 16 + l15 - 2048;
            int h = c >> 6, d = c & 63;
#pragma unroll
            for (int i = 0; i < 4; ++i) {
                int m0 = aTile + aOff + i * 16 + quad * 4;
                int b = m0 >> 11, seq0 = m0 & 2047;
                ushort4 o;
                o.x = f2bf(acc[i][j][0]); o.y = f2bf(acc[i][j][1]);
                o.z = f2bf(acc[i][j][2]); o.w = f2bf(acc[i][j][3]);
                *(ushort4*)(v_t + (((size_t)(b * 16 + h)) * 64 + d) * SEQ + seq0) = o;
            }
        }
    }
}

// ---------------- Final GEMM + bias, f32 out (BN=64, C^T -> float4 stores) ------
__global__ __launch_bounds__(256) void gemm_out_kernel(const unsigned short* __restrict__ A,
                                                       const unsigned short* __restrict__ Bt,
                                                       const float* __restrict__ bias,
                                                       float* __restrict__ C) {
    __shared__ __align__(16) unsigned short As[128][32];
    __shared__ __align__(16) unsigned short Bs[64][32];
    int t = threadIdx.x, w = t >> 6, L = t & 63, l15 = L & 15, quad = L >> 4;
    int aTile = blockIdx.y * 128, bTile = blockIdx.x * 64;
    v4f acc[2][4] = {};
    mm_core2<64, true>(A, Bt, DIM, aTile, bTile, As, Bs, acc);
#pragma unroll
    for (int j = 0; j < 4; ++j) {
        int n = bTile + j * 16 + quad * 4;    // 4 consecutive cols
        float4 bv = *(const float4*)(bias + n);
#pragma unroll
        for (int i = 0; i < 2; ++i) {
            int m = aTile + w * 32 + i * 16 + l15;
            float4 o = make_float4(acc[i][j][0] + bv.x, acc[i][j][1] + bv.y,
                                   acc[i][j][2] + bv.z, acc[i][j][3] + bv.w);
            *(float4*)(C + (size_t)m * DIM + n) = o;
        }
    }
}

// ---------------- MFMA flash attention (S^T formulation) ----------------
// block = 128 Q rows, 4 waves x 32 Q rows; 64 keys/iter staged once per block.
__global__ __launch_bounds__(256) void attn_kernel(const unsigned short* __restrict__ q_h,
                                                   const unsigned short* __restrict__ k_h,
                                                   const unsigned short* __restrict__ v_t,
                                                   unsigned short* __restrict__ ao) {
    __shared__ __align__(16) unsigned short KF[8 * 64 * 8];     // 8 KB
    __shared__ __align__(16) unsigned short VF[8 * 64 * 8];     // 8 KB
    __shared__ __align__(16) unsigned short Pld[4][2][16 * 72]; // 18 KB
    int qt = blockIdx.x, h = blockIdx.y, b = blockIdx.z;
    int bh = b * HEADS + h;
    int w = threadIdx.x >> 6;
    int L = threadIdx.x & 63, l15 = L & 15, quad = L >> 4;

    const unsigned short* qp = q_h + ((size_t)bh * SEQ + qt * 128 + w * 32 + l15) * 64 + quad * 8;
    v8s qf[2][2];
    qf[0][0] = *(const v8s*)(qp);
    qf[0][1] = *(const v8s*)(qp + 32);
    qf[1][0] = *(const v8s*)(qp + 16 * 64);
    qf[1][1] = *(const v8s*)(qp + 16 * 64 + 32);

    const unsigned short* kstage = k_h + ((size_t)bh * SEQ + w * 16 + l15) * 64 + quad * 8;
    const unsigned short* vstage = v_t + ((size_t)bh * 64 + w * 16 + l15) * SEQ + quad * 8;

    v4f o[2][4] = {};
    v4f lacc[2] = {};
    const short ob = (short)0x3F80;   // bf16 1.0
    const v8s ones = {ob, ob, ob, ob, ob, ob, ob, ob};

    v8s ks0 = *(const v8s*)(kstage);
    v8s ks1 = *(const v8s*)(kstage + 32);
    v8s vs0 = *(const v8s*)(vstage);
    v8s vs1 = *(const v8s*)(vstage + 32);

    for (int j0 = 0; j0 < SEQ; j0 += 64) {
        __syncthreads();
        *(v8s*)&KF[((w * 2 + 0) * 64 + L) * 8] = ks0;
        *(v8s*)&KF[((w * 2 + 1) * 64 + L) * 8] = ks1;
        *(v8s*)&VF[((w * 2 + 0) * 64 + L) * 8] = vs0;
        *(v8s*)&VF[((w * 2 + 1) * 64 + L) * 8] = vs1;
        __syncthreads();
        if (j0 + 64 < SEQ) {
            ks0 = *(const v8s*)(kstage + (size_t)(j0 + 64) * 64);
            ks1 = *(const v8s*)(kstage + (size_t)(j0 + 64) * 64 + 32);
            vs0 = *(const v8s*)(vstage + j0 + 64);
            vs1 = *(const v8s*)(vstage + j0 + 64 + 32);
        }
        v8s kf[4][2], vf[4][2];
#pragma unroll
        for (int jt = 0; jt < 4; ++jt) {
            kf[jt][0] = *(const v8s*)&KF[((jt * 2 + 0) * 64 + L) * 8];
            kf[jt][1] = *(const v8s*)&KF[((jt * 2 + 1) * 64 + L) * 8];
            vf[jt][0] = *(const v8s*)&VF[((jt * 2 + 0) * 64 + L) * 8];
            vf[jt][1] = *(const v8s*)&VF[((jt * 2 + 1) * 64 + L) * 8];
        }
        v4f s[2][4] = {};
#pragma unroll
        for (int m = 0; m < 2; ++m)
#pragma unroll
            for (int jt = 0; jt < 4; ++jt) {
                s[m][jt] = __builtin_amdgcn_mfma_f32_16x16x32_bf16(kf[jt][0], qf[m][0], s[m][jt], 0, 0, 0);
                s[m][jt] = __builtin_amdgcn_mfma_f32_16x16x32_bf16(kf[jt][1], qf[m][1], s[m][jt], 0, 0, 0);
            }
#pragma unroll
        for (int m = 0; m < 2; ++m)
#pragma unroll
            for (int jt = 0; jt < 4; ++jt) {
                float p0 = fast_exp2(s[m][jt][0] * SCALE_LOG2E);
                float p1 = fast_exp2(s[m][jt][1] * SCALE_LOG2E);
                float p2 = fast_exp2(s[m][jt][2] * SCALE_LOG2E);
                float p3 = fast_exp2(s[m][jt][3] * SCALE_LOG2E);
                uint2 pk;
                pk.x = pk_bf2(p1, p0);
                pk.y = pk_bf2(p3, p2);
                *(uint2*)&Pld[w][m][l15 * 72 + jt * 16 + quad * 4] = pk;
            }
#pragma unroll
        for (int m = 0; m < 2; ++m) {
            v8s pb0 = *(const v8s*)&Pld[w][m][l15 * 72 + quad * 8];
            v8s pb1 = *(const v8s*)&Pld[w][m][l15 * 72 + 32 + quad * 8];
#pragma unroll
            for (int dt = 0; dt < 4; ++dt) {
                o[m][dt] = __builtin_amdgcn_mfma_f32_16x16x32_bf16(vf[dt][0], pb0, o[m][dt], 0, 0, 0);
                o[m][dt] = __builtin_amdgcn_mfma_f32_16x16x32_bf16(vf[dt][1], pb1, o[m][dt], 0, 0, 0);
            }
            lacc[m] = __builtin_amdgcn_mfma_f32_16x16x32_bf16(ones, pb0, lacc[m], 0, 0, 0);
            lacc[m] = __builtin_amdgcn_mfma_f32_16x16x32_bf16(ones, pb1, lacc[m], 0, 0, 0);
        }
    }
#pragma unroll
    for (int m = 0; m < 2; ++m) {
        float inv = 1.f / lacc[m][0];
        int rowg = b * SEQ + qt * 128 + w * 32 + m * 16 + l15;
#pragma unroll
        for (int dt = 0; dt < 4; ++dt) {
            ushort4 ov;
            ov.x = f2bf(o[m][dt][0] * inv);
            ov.y = f2bf(o[m][dt][1] * inv);
            ov.z = f2bf(o[m][dt][2] * inv);
            ov.w = f2bf(o[m][dt][3] * inv);
            *(ushort4*)(ao + (size_t)rowg * DIM + h * 64 + dt * 16 + quad * 4) = ov;
        }
    }
}

extern "C" void kernel_launch(void* const* d_in, const int* in_sizes, int n_in,
                              void* d_out, int out_size, void* d_ws, size_t ws_size,
                              hipStream_t stream) {
    const float* x     = (const float*)d_in[0];
    const float* gamma = (const float*)d_in[1];
    const float* beta  = (const float*)d_in[2];
    const float* Wqk   = (const float*)d_in[3];
    const float* Wv    = (const float*)d_in[4];
    const float* Wout  = (const float*)d_in[5];
    const float* bout  = (const float*)d_in[6];
    float* out = (float*)d_out;

    unsigned short* ws = (unsigned short*)d_ws;
    unsigned short* xn    = ws;                            // 4096*1024
    unsigned short* Wt_qk = xn + (size_t)ROWS * DIM;       // 2048*1024
    unsigned short* Wt_v  = Wt_qk + (size_t)2048 * DIM;    // 1024*1024 (contiguous after qk)
    unsigned short* Wt_o  = Wt_v + (size_t)DIM * DIM;      // 1024*1024
    unsigned short* q_h   = Wt_o + (size_t)DIM * DIM;      // 4096*1024
    unsigned short* k_h   = q_h + (size_t)ROWS * DIM;      // 4096*1024
    unsigned short* v_t   = k_h + (size_t)ROWS * DIM;      // 4096*1024
    unsigned short* ao    = v_t + (size_t)ROWS * DIM;      // 4096*1024

    ln_kernel<<<ROWS, 256, 0, stream>>>(x, gamma, beta, xn);
    tr_all_kernel<<<dim3(32, 16, 3), 256, 0, stream>>>(Wqk, Wv, Wout, Wt_qk, Wt_v, Wt_o);
    gemm_qkv_kernel<<<dim3(3072 / 128, ROWS / 128), 256, 0, stream>>>(xn, Wt_qk, q_h, k_h, v_t);
    attn_kernel<<<dim3(SEQ / 128, HEADS, BATCH), 256, 0, stream>>>(q_h, k_h, v_t, ao);
    gemm_out_kernel<<<dim3(DIM / 64, ROWS / 128), 256, 0, stream>>>(ao, Wt_o, bout, out);
}